// Round 1
// baseline (253.703 us; speedup 1.0000x reference)
//
#include <hip/hip_runtime.h>
#include <hip/hip_bf16.h>
#include <float.h>

#define DEVI __device__ __forceinline__

namespace {

constexpr int NB   = 8;     // batch
constexpr int CD   = 256;   // dense channels
constexpr int CS   = 512;   // sparse channels
constexpr int MM   = 4096;  // dense points
constexpr int SS   = 1024;  // sparse points
constexpr int NN   = 4096;  // pcd points
constexpr int KTOT = 768;   // CD + CS
constexpr int OC   = 256;   // output channels
constexpr float KEPS  = 1e-8f;
constexpr float BNEPS = 1e-5f;
constexpr float SLOPE = 0.2f;

// workspace layout (bytes) — total ~18 MB
constexpr size_t OFF_SPT  = 0;                          // float [NB][SS][CS] transposed sparse
constexpr size_t SZ_SPT   = (size_t)NB * SS * CS * 4;   // 16,777,216
constexpr size_t OFF_IDX3 = OFF_SPT + SZ_SPT;           // int   [NB][MM][3]
constexpr size_t SZ_IDX3  = (size_t)NB * MM * 3 * 4;    // 393,216
constexpr size_t OFF_W3   = OFF_IDX3 + SZ_IDX3;         // float [NB][MM][3]
constexpr size_t OFF_WBF  = OFF_W3 + SZ_IDX3;           // bf16  [OC][KTOT]
constexpr size_t SZ_WBF   = (size_t)OC * KTOT * 2;      // 393,216
constexpr size_t OFF_MU   = OFF_WBF + SZ_WBF;           // float [OC]
constexpr size_t OFF_RS   = OFF_MU + OC * 4;            // float [OC]

typedef __attribute__((ext_vector_type(8))) short s16x8;
typedef __attribute__((ext_vector_type(4))) float f32x4;

// float -> bf16 (RNE), returned as raw short
DEVI short f2bf(float f) {
  union { float f; unsigned u; } c; c.f = f;
  unsigned r = c.u + 0x7fffu + ((c.u >> 16) & 1u);
  return (short)(r >> 16);
}

// ---------------------------------------------------------------- conv_w -> bf16
__global__ void k_wcast(const float* __restrict__ w, short* __restrict__ wbf) {
  int i = blockIdx.x * 256 + threadIdx.x;   // grid covers OC*KTOT exactly
  wbf[i] = f2bf(w[i]);
}

// ------------------------------------------- sparse_data [b][c][s] -> spt [b][s][c]
__global__ void k_transpose(const float* __restrict__ sp, float* __restrict__ spt) {
  __shared__ float t[32][33];
  int blk = blockIdx.x;                 // 8 * 16 * 32 = 4096 blocks
  int st = blk & 31;                    // s-tile
  int ct = (blk >> 5) & 15;             // c-tile
  int b  = blk >> 9;
  int tx = threadIdx.x & 31, ty = threadIdx.x >> 5;   // 32 x 8
  int c0 = ct * 32, s0 = st * 32;
#pragma unroll
  for (int r = 0; r < 32; r += 8)
    t[ty + r][tx] = sp[((size_t)(b * CS + c0 + ty + r)) * SS + s0 + tx];
  __syncthreads();
#pragma unroll
  for (int r = 0; r < 32; r += 8)
    spt[((size_t)(b * SS + s0 + ty + r)) * CS + c0 + tx] = t[tx][ty + r];
}

// ---------------------------------------------------------------- KNN top-3
// one wave per dense point; sparse xyz staged in LDS; butterfly top-3 merge
__global__ void k_knn(const int* __restrict__ didx, const int* __restrict__ sidx,
                      const float* __restrict__ pcd,
                      int* __restrict__ idx3, float* __restrict__ w3,
                      float* __restrict__ outIdxF) {
  __shared__ float sx[SS], sy[SS], sz[SS];
  int blk = blockIdx.x;                 // 8 * 64 = 512 blocks, 64 rows each
  int b   = blk >> 6;
  int m0  = (blk & 63) << 6;
  int tid = threadIdx.x;
  const float* pb = pcd + (size_t)b * 3 * NN;
  for (int s = tid; s < SS; s += 256) {
    int si = sidx[b * SS + s];
    sx[s] = pb[si]; sy[s] = pb[NN + si]; sz[s] = pb[2 * NN + si];
  }
  if (tid < 64) {  // output 1: dense_idx as float
    int row = b * MM + m0 + tid;
    outIdxF[row] = (float)didx[row];
  }
  __syncthreads();
  int wv = tid >> 6, lane = tid & 63;
#pragma unroll 1
  for (int r = 0; r < 16; ++r) {
    int m  = m0 + wv * 16 + r;
    int di = didx[b * MM + m];
    float px = pb[di], py = pb[NN + di], pz = pb[2 * NN + di];
    float d0 = FLT_MAX, d1 = FLT_MAX, d2 = FLT_MAX;
    int   i0 = 0, i1 = 0, i2 = 0;
    for (int s = lane; s < SS; s += 64) {
      float dx = sx[s] - px, dy = sy[s] - py, dz = sz[s] - pz;
      float d  = dx * dx + dy * dy + dz * dz;
      if (d < d2) {
        if (d < d1) {
          d2 = d1; i2 = i1;
          if (d < d0) { d1 = d0; i1 = i0; d0 = d; i0 = s; }
          else        { d1 = d;  i1 = s; }
        } else { d2 = d; i2 = s; }
      }
    }
    // merge sorted top-3 across lanes (xor butterfly)
#pragma unroll
    for (int off = 1; off < 64; off <<= 1) {
      float e0 = __shfl_xor(d0, off), e1 = __shfl_xor(d1, off), e2 = __shfl_xor(d2, off);
      int   j0 = __shfl_xor(i0, off), j1 = __shfl_xor(i1, off), j2 = __shfl_xor(i2, off);
      bool s0 = d0 <= e0;
      float n0 = s0 ? d0 : e0; int k0 = s0 ? i0 : j0;
      float u0 = s0 ? d1 : d0; int ui0 = s0 ? i1 : i0;
      float u1 = s0 ? d2 : d1; int ui1 = s0 ? i2 : i1;
      float v0 = s0 ? e0 : e1; int vi0 = s0 ? j0 : j1;
      float v1 = s0 ? e1 : e2; int vi1 = s0 ? j1 : j2;
      bool s1 = u0 <= v0;
      float n1 = s1 ? u0 : v0; int k1 = s1 ? ui0 : vi0;
      float t0 = s1 ? u1 : u0; int ti0 = s1 ? ui1 : ui0;
      float t1 = s1 ? v0 : v1; int ti1 = s1 ? vi0 : vi1;
      bool s2 = t0 <= t1;
      float n2 = s2 ? t0 : t1; int k2 = s2 ? ti0 : ti1;
      d0 = n0; d1 = n1; d2 = n2; i0 = k0; i1 = k1; i2 = k2;
    }
    if (lane == 0) {
      float w0 = 1.f / (d0 + KEPS), w1 = 1.f / (d1 + KEPS), w2 = 1.f / (d2 + KEPS);
      float inv = 1.f / (w0 + w1 + w2);
      int base = (b * MM + m) * 3;
      idx3[base] = i0; idx3[base + 1] = i1; idx3[base + 2] = i2;
      w3[base] = w0 * inv; w3[base + 1] = w1 * inv; w3[base + 2] = w2 * inv;
    }
  }
}

// ---------------------------------------------------------------- fused GEMM
// y[b,o,m] = sum_k W[o,k] * x[b,k,m],  x = [dense_data ; knn-interp(spt)]
// 128x128 tile, BK=32, 4 waves each 64x64 (4x4 grid of 16x16x32 MFMA)
__global__ __launch_bounds__(256) void k_gemm(
    const float* __restrict__ dense, const float* __restrict__ spt,
    const int* __restrict__ idx3, const float* __restrict__ w3,
    const short* __restrict__ wbf, float* __restrict__ y) {
  __shared__ short Al[128 * 40];   // [o][k] pad->40 (80B rows, 16B aligned)
  __shared__ short Xl[128 * 40];   // [m][k] pad->40
  __shared__ int   mi3[128 * 3];
  __shared__ float mw3[128 * 3];

  int blk = blockIdx.x;            // 8 * 2 * 32 = 512 blocks
  int mt = blk & 31, ot = (blk >> 5) & 1, b = blk >> 6;
  int m0 = mt << 7, o0 = ot << 7;
  int tid = threadIdx.x;

  {
    int base = (b * MM + m0) * 3;
    for (int i = tid; i < 384; i += 256) { mi3[i] = idx3[base + i]; mw3[i] = w3[base + i]; }
  }

  f32x4 acc[4][4] = {};
  int wv = tid >> 6, lane = tid & 63;
  int wo = (wv >> 1) << 6, wm = (wv & 1) << 6;
  int lo = lane & 15, quad = lane >> 4;

  for (int k0 = 0; k0 < KTOT; k0 += 32) {
    __syncthreads();
    // ---- stage A (weights, bf16, row-major [o][768])
    {
      const unsigned short* W = (const unsigned short*)wbf;
#pragma unroll
      for (int r = 0; r < 2; ++r) {
        int lin = r * 256 + tid;          // 512 chunks of 16B
        int oo = lin >> 2, q = lin & 3;
        uint4 v = *(const uint4*)(W + (size_t)(o0 + oo) * KTOT + k0 + q * 8);
        *(uint4*)(&Al[oo * 40 + q * 8]) = v;
      }
    }
    // ---- stage X transposed [m][k]
    if (k0 < CD) {
#pragma unroll
      for (int r = 0; r < 4; ++r) {
        int lin = r * 256 + tid;          // 1024 float4 chunks (32 m4 x 32 k)
        int m4 = lin & 31, kk = lin >> 5;
        float4 v = *(const float4*)(dense + (size_t)(b * CD + k0 + kk) * MM + m0 + m4 * 4);
        Xl[(m4 * 4 + 0) * 40 + kk] = f2bf(v.x);
        Xl[(m4 * 4 + 1) * 40 + kk] = f2bf(v.y);
        Xl[(m4 * 4 + 2) * 40 + kk] = f2bf(v.z);
        Xl[(m4 * 4 + 3) * 40 + kk] = f2bf(v.w);
      }
    } else {
      int c0 = k0 - CD;
#pragma unroll
      for (int r = 0; r < 4; ++r) {
        int lin = r * 256 + tid;          // 1024 chunks (128 m x 8 kq)
        int kq = lin & 7, mw = lin >> 3;
        float4 a = {0.f, 0.f, 0.f, 0.f};
#pragma unroll
        for (int j = 0; j < 3; ++j) {
          int row = mi3[mw * 3 + j]; float wj = mw3[mw * 3 + j];
          float4 v = *(const float4*)(spt + (size_t)(b * SS + row) * CS + c0 + kq * 4);
          a.x += wj * v.x; a.y += wj * v.y; a.z += wj * v.z; a.w += wj * v.w;
        }
        ushort4 p;
        p.x = (unsigned short)f2bf(a.x); p.y = (unsigned short)f2bf(a.y);
        p.z = (unsigned short)f2bf(a.z); p.w = (unsigned short)f2bf(a.w);
        *(ushort4*)(&Xl[mw * 40 + kq * 4]) = p;
      }
    }
    __syncthreads();
    // ---- MFMA
    s16x8 af[4], bf[4];
#pragma unroll
    for (int i = 0; i < 4; ++i)
      af[i] = *(const s16x8*)(&Al[(wo + i * 16 + lo) * 40 + quad * 8]);
#pragma unroll
    for (int i = 0; i < 4; ++i)
      bf[i] = *(const s16x8*)(&Xl[(wm + i * 16 + lo) * 40 + quad * 8]);
#pragma unroll
    for (int i = 0; i < 4; ++i)
#pragma unroll
      for (int j = 0; j < 4; ++j)
        acc[i][j] = __builtin_amdgcn_mfma_f32_16x16x32_bf16(af[i], bf[j], acc[i][j], 0, 0, 0);
  }

  // ---- epilogue: raw y (pre-BN) into d_out region 0
#pragma unroll
  for (int i = 0; i < 4; ++i) {
    int oo = o0 + wo + i * 16 + quad * 4;
#pragma unroll
    for (int j = 0; j < 4; ++j) {
      int mm = m0 + wm + j * 16 + lo;
      float* dst = y + (size_t)(b * OC + oo) * MM + mm;
#pragma unroll
      for (int r2 = 0; r2 < 4; ++r2)
        dst[(size_t)r2 * MM] = acc[i][j][r2];
    }
  }
}

// ---------------------------------------------------------------- BN stats
__global__ void k_stats(const float* __restrict__ y, float* __restrict__ mu,
                        float* __restrict__ rs) {
  int o = blockIdx.x, tid = threadIdx.x;
  float s = 0.f, s2 = 0.f;
  for (int b = 0; b < NB; ++b) {
    const float4* row = (const float4*)(y + (size_t)(b * OC + o) * MM);
    for (int m = tid; m < MM / 4; m += 256) {
      float4 v = row[m];
      s  += v.x + v.y + v.z + v.w;
      s2 += v.x * v.x + v.y * v.y + v.z * v.z + v.w * v.w;
    }
  }
#pragma unroll
  for (int off = 32; off; off >>= 1) { s += __shfl_down(s, off); s2 += __shfl_down(s2, off); }
  __shared__ float as[4], as2[4];
  int wv = tid >> 6, lane = tid & 63;
  if (lane == 0) { as[wv] = s; as2[wv] = s2; }
  __syncthreads();
  if (tid == 0) {
    float S  = as[0] + as[1] + as[2] + as[3];
    float S2 = as2[0] + as2[1] + as2[2] + as2[3];
    float mn = S / (float)(NB * MM);
    float vr = S2 / (float)(NB * MM) - mn * mn;
    mu[o] = mn;
    rs[o] = rsqrtf(vr + BNEPS);
  }
}

// ---------------------------------------------------------------- BN apply + LeakyReLU
__global__ void k_norm(float* __restrict__ y, const float* __restrict__ mu,
                       const float* __restrict__ rs, const float* __restrict__ gamma,
                       const float* __restrict__ beta) {
  int i = blockIdx.x * 256 + threadIdx.x;   // float4 index; grid covers exactly
  int o = (i >> 10) & 255;                  // 1024 float4 per (b,o) row
  float mn = mu[o], a = rs[o] * gamma[o], be = beta[o];
  float4 v = ((const float4*)y)[i];
  float t;
  t = (v.x - mn) * a + be; v.x = t >= 0.f ? t : SLOPE * t;
  t = (v.y - mn) * a + be; v.y = t >= 0.f ? t : SLOPE * t;
  t = (v.z - mn) * a + be; v.z = t >= 0.f ? t : SLOPE * t;
  t = (v.w - mn) * a + be; v.w = t >= 0.f ? t : SLOPE * t;
  ((float4*)y)[i] = v;
}

}  // namespace

extern "C" void kernel_launch(void* const* d_in, const int* in_sizes, int n_in,
                              void* d_out, int out_size, void* d_ws, size_t ws_size,
                              hipStream_t stream) {
  const float* dense = (const float*)d_in[0];
  const int*   didx  = (const int*)d_in[1];
  const float* sp    = (const float*)d_in[2];
  const int*   sidx  = (const int*)d_in[3];
  const float* pcd   = (const float*)d_in[4];
  const float* convw = (const float*)d_in[5];
  const float* gamma = (const float*)d_in[6];
  const float* beta  = (const float*)d_in[7];

  float* y = (float*)d_out;                       // [8][256][4096] raw -> normalized in place
  float* outIdxF = y + (size_t)NB * OC * MM;      // output 1: dense_idx as float

  char* ws = (char*)d_ws;                         // needs ~18 MB
  float* spt  = (float*)(ws + OFF_SPT);
  int*   idx3 = (int*)(ws + OFF_IDX3);
  float* w3   = (float*)(ws + OFF_W3);
  short* wbf  = (short*)(ws + OFF_WBF);
  float* mu   = (float*)(ws + OFF_MU);
  float* rs   = (float*)(ws + OFF_RS);

  k_wcast    <<<(OC * KTOT) / 256, 256, 0, stream>>>(convw, wbf);
  k_transpose<<<NB * (CS / 32) * (SS / 32), 256, 0, stream>>>(sp, spt);
  k_knn      <<<NB * (MM / 64), 256, 0, stream>>>(didx, sidx, pcd, idx3, w3, outIdxF);
  k_gemm     <<<NB * 2 * (MM / 128), 256, 0, stream>>>(dense, spt, idx3, w3, wbf, y);
  k_stats    <<<OC, 256, 0, stream>>>(y, mu, rs);
  k_norm     <<<(NB * OC * MM / 4) / 256, 256, 0, stream>>>(y, mu, rs, gamma, beta);
}

// Round 2
// 208.773 us; speedup vs baseline: 1.2152x; 1.2152x over previous
//
#include <hip/hip_runtime.h>
#include <hip/hip_bf16.h>
#include <float.h>

#define DEVI __device__ __forceinline__

namespace {

constexpr int NB   = 8;     // batch
constexpr int CD   = 256;   // dense channels
constexpr int CS   = 512;   // sparse channels
constexpr int MM   = 4096;  // dense points
constexpr int SS   = 1024;  // sparse points
constexpr int NN   = 4096;  // pcd points
constexpr int KTOT = 768;   // CD + CS
constexpr int OC   = 256;   // output channels
constexpr float KEPS  = 1e-8f;
constexpr float BNEPS = 1e-5f;
constexpr float SLOPE = 0.2f;

// workspace layout (bytes) — total ~18 MB
constexpr size_t OFF_SPT  = 0;                          // float [NB][SS][CS] transposed sparse
constexpr size_t SZ_SPT   = (size_t)NB * SS * CS * 4;   // 16,777,216
constexpr size_t OFF_IDX3 = OFF_SPT + SZ_SPT;           // int   [NB][MM][3]
constexpr size_t SZ_IDX3  = (size_t)NB * MM * 3 * 4;    // 393,216
constexpr size_t OFF_W3   = OFF_IDX3 + SZ_IDX3;         // float [NB][MM][3]
constexpr size_t OFF_WBF  = OFF_W3 + SZ_IDX3;           // bf16  [OC][KTOT]
constexpr size_t SZ_WBF   = (size_t)OC * KTOT * 2;      // 393,216
constexpr size_t OFF_MU   = OFF_WBF + SZ_WBF;           // float [OC]
constexpr size_t OFF_RS   = OFF_MU + OC * 4;            // float [OC]

typedef __attribute__((ext_vector_type(8))) short s16x8;
typedef __attribute__((ext_vector_type(4))) float f32x4;

// float -> bf16 (RNE), returned as raw short
DEVI short f2bf(float f) {
  union { float f; unsigned u; } c; c.f = f;
  unsigned r = c.u + 0x7fffu + ((c.u >> 16) & 1u);
  return (short)(r >> 16);
}

// ---------------------------------------------------------------- conv_w -> bf16
__global__ void k_wcast(const float* __restrict__ w, short* __restrict__ wbf) {
  int i = blockIdx.x * 256 + threadIdx.x;   // grid covers OC*KTOT exactly
  wbf[i] = f2bf(w[i]);
}

// ------------------------------------------- sparse_data [b][c][s] -> spt [b][s][c]
__global__ void k_transpose(const float* __restrict__ sp, float* __restrict__ spt) {
  __shared__ float t[32][33];
  int blk = blockIdx.x;                 // 8 * 16 * 32 = 4096 blocks
  int st = blk & 31;                    // s-tile
  int ct = (blk >> 5) & 15;             // c-tile
  int b  = blk >> 9;
  int tx = threadIdx.x & 31, ty = threadIdx.x >> 5;   // 32 x 8
  int c0 = ct * 32, s0 = st * 32;
#pragma unroll
  for (int r = 0; r < 32; r += 8)
    t[ty + r][tx] = sp[((size_t)(b * CS + c0 + ty + r)) * SS + s0 + tx];
  __syncthreads();
#pragma unroll
  for (int r = 0; r < 32; r += 8)
    spt[((size_t)(b * SS + s0 + ty + r)) * CS + c0 + tx] = t[tx][ty + r];
}

// ---------------------------------------------------------------- KNN top-3
// one LANE per dense point (64 points/block), 4 candidate chunks of 256 across
// the 4 waves; branchless register insertion network; LDS merge of partials.
__global__ __launch_bounds__(256) void k_knn(
    const int* __restrict__ didx, const int* __restrict__ sidx,
    const float* __restrict__ pcd,
    int* __restrict__ idx3, float* __restrict__ w3,
    float* __restrict__ outIdxF) {
  __shared__ float4 sxyz[SS];              // 16 KB candidate coords
  __shared__ float  pd[4][64][3];          // partial top-3 dists
  __shared__ int    pi[4][64][3];          // partial top-3 idxs

  int blk = blockIdx.x;                    // 8 * 64 = 512 blocks
  int b   = blk >> 6;
  int m0  = (blk & 63) << 6;
  int tid = threadIdx.x;
  const float* pb = pcd + (size_t)b * 3 * NN;

  for (int s = tid; s < SS; s += 256) {
    int si = sidx[b * SS + s];
    sxyz[s] = make_float4(pb[si], pb[NN + si], pb[2 * NN + si], 0.f);
  }

  int p     = tid & 63;                    // point within tile
  int chunk = tid >> 6;                    // candidate chunk
  int m     = m0 + p;
  int di    = didx[b * MM + m];
  float px = pb[di], py = pb[NN + di], pz = pb[2 * NN + di];

  if (chunk == 0) outIdxF[b * MM + m] = (float)di;   // output 1

  __syncthreads();

  float d0 = FLT_MAX, d1 = FLT_MAX, d2 = FLT_MAX;
  int   i0 = 0, i1 = 0, i2 = 0;
  int s0c = chunk << 8;
#pragma unroll 4
  for (int t = 0; t < 256; ++t) {
    int s = s0c + t;
    float4 c = sxyz[s];
    float dx = c.x - px, dy = c.y - py, dz = c.z - pz;
    float d  = dx * dx + dy * dy + dz * dz;
    bool lt0 = d < d0, lt1 = d < d1, lt2 = d < d2;
    d2 = lt1 ? d1 : (lt2 ? d : d2);  i2 = lt1 ? i1 : (lt2 ? s : i2);
    d1 = lt0 ? d0 : (lt1 ? d : d1);  i1 = lt0 ? i0 : (lt1 ? s : i1);
    d0 = lt0 ? d  : d0;              i0 = lt0 ? s : i0;
  }
  pd[chunk][p][0] = d0; pd[chunk][p][1] = d1; pd[chunk][p][2] = d2;
  pi[chunk][p][0] = i0; pi[chunk][p][1] = i1; pi[chunk][p][2] = i2;
  __syncthreads();

  if (tid < 64) {
    float e0 = FLT_MAX, e1 = FLT_MAX, e2 = FLT_MAX;
    int   j0 = 0, j1 = 0, j2 = 0;
#pragma unroll
    for (int c = 0; c < 4; ++c)
#pragma unroll
      for (int r = 0; r < 3; ++r) {
        float d = pd[c][p][r]; int s = pi[c][p][r];
        bool lt0 = d < e0, lt1 = d < e1, lt2 = d < e2;
        e2 = lt1 ? e1 : (lt2 ? d : e2);  j2 = lt1 ? j1 : (lt2 ? s : j2);
        e1 = lt0 ? e0 : (lt1 ? d : e1);  j1 = lt0 ? j0 : (lt1 ? s : j1);
        e0 = lt0 ? d  : e0;              j0 = lt0 ? s : j0;
      }
    float w0 = 1.f / (e0 + KEPS), w1 = 1.f / (e1 + KEPS), w2 = 1.f / (e2 + KEPS);
    float inv = 1.f / (w0 + w1 + w2);
    int base = (b * MM + m) * 3;
    idx3[base] = j0; idx3[base + 1] = j1; idx3[base + 2] = j2;
    w3[base] = w0 * inv; w3[base + 1] = w1 * inv; w3[base + 2] = w2 * inv;
  }
}

// ---------------------------------------------------------------- fused GEMM
// y[b,o,m] = sum_k W[o,k] * x[b,k,m],  x = [dense_data ; knn-interp(spt)]
// 128x128 tile, BK=32, 4 waves each 64x64 (4x4 grid of 16x16x32 MFMA)
__global__ __launch_bounds__(256) void k_gemm(
    const float* __restrict__ dense, const float* __restrict__ spt,
    const int* __restrict__ idx3, const float* __restrict__ w3,
    const short* __restrict__ wbf, float* __restrict__ y) {
  __shared__ short Al[128 * 40];   // [o][k] pad->40 (80B rows, 16B aligned)
  __shared__ short Xl[128 * 40];   // [m][k] pad->40
  __shared__ int   mi3[128 * 3];
  __shared__ float mw3[128 * 3];

  int blk = blockIdx.x;            // 8 * 2 * 32 = 512 blocks
  int mt = blk & 31, ot = (blk >> 5) & 1, b = blk >> 6;
  int m0 = mt << 7, o0 = ot << 7;
  int tid = threadIdx.x;

  {
    int base = (b * MM + m0) * 3;
    for (int i = tid; i < 384; i += 256) { mi3[i] = idx3[base + i]; mw3[i] = w3[base + i]; }
  }

  f32x4 acc[4][4] = {};
  int wv = tid >> 6, lane = tid & 63;
  int wo = (wv >> 1) << 6, wm = (wv & 1) << 6;
  int lo = lane & 15, quad = lane >> 4;

  for (int k0 = 0; k0 < KTOT; k0 += 32) {
    __syncthreads();
    // ---- stage A (weights, bf16, row-major [o][768])
    {
      const unsigned short* W = (const unsigned short*)wbf;
#pragma unroll
      for (int r = 0; r < 2; ++r) {
        int lin = r * 256 + tid;          // 512 chunks of 16B
        int oo = lin >> 2, q = lin & 3;
        uint4 v = *(const uint4*)(W + (size_t)(o0 + oo) * KTOT + k0 + q * 8);
        *(uint4*)(&Al[oo * 40 + q * 8]) = v;
      }
    }
    // ---- stage X transposed [m][k]
    if (k0 < CD) {
#pragma unroll
      for (int r = 0; r < 4; ++r) {
        int lin = r * 256 + tid;          // 1024 float4 chunks (32 m4 x 32 k)
        int m4 = lin & 31, kk = lin >> 5;
        float4 v = *(const float4*)(dense + (size_t)(b * CD + k0 + kk) * MM + m0 + m4 * 4);
        Xl[(m4 * 4 + 0) * 40 + kk] = f2bf(v.x);
        Xl[(m4 * 4 + 1) * 40 + kk] = f2bf(v.y);
        Xl[(m4 * 4 + 2) * 40 + kk] = f2bf(v.z);
        Xl[(m4 * 4 + 3) * 40 + kk] = f2bf(v.w);
      }
    } else {
      int c0 = k0 - CD;
#pragma unroll
      for (int r = 0; r < 4; ++r) {
        int lin = r * 256 + tid;          // 1024 chunks (128 m x 8 kq)
        int kq = lin & 7, mw = lin >> 3;
        float4 a = {0.f, 0.f, 0.f, 0.f};
#pragma unroll
        for (int j = 0; j < 3; ++j) {
          int row = mi3[mw * 3 + j]; float wj = mw3[mw * 3 + j];
          float4 v = *(const float4*)(spt + (size_t)(b * SS + row) * CS + c0 + kq * 4);
          a.x += wj * v.x; a.y += wj * v.y; a.z += wj * v.z; a.w += wj * v.w;
        }
        ushort4 p;
        p.x = (unsigned short)f2bf(a.x); p.y = (unsigned short)f2bf(a.y);
        p.z = (unsigned short)f2bf(a.z); p.w = (unsigned short)f2bf(a.w);
        *(ushort4*)(&Xl[mw * 40 + kq * 4]) = p;
      }
    }
    __syncthreads();
    // ---- MFMA
    s16x8 af[4], bf[4];
#pragma unroll
    for (int i = 0; i < 4; ++i)
      af[i] = *(const s16x8*)(&Al[(wo + i * 16 + lo) * 40 + quad * 8]);
#pragma unroll
    for (int i = 0; i < 4; ++i)
      bf[i] = *(const s16x8*)(&Xl[(wm + i * 16 + lo) * 40 + quad * 8]);
#pragma unroll
    for (int i = 0; i < 4; ++i)
#pragma unroll
      for (int j = 0; j < 4; ++j)
        acc[i][j] = __builtin_amdgcn_mfma_f32_16x16x32_bf16(af[i], bf[j], acc[i][j], 0, 0, 0);
  }

  // ---- epilogue: raw y (pre-BN) into d_out region 0
#pragma unroll
  for (int i = 0; i < 4; ++i) {
    int oo = o0 + wo + i * 16 + quad * 4;
#pragma unroll
    for (int j = 0; j < 4; ++j) {
      int mm = m0 + wm + j * 16 + lo;
      float* dst = y + (size_t)(b * OC + oo) * MM + mm;
#pragma unroll
      for (int r2 = 0; r2 < 4; ++r2)
        dst[(size_t)r2 * MM] = acc[i][j][r2];
    }
  }
}

// ---------------------------------------------------------------- BN stats
__global__ void k_stats(const float* __restrict__ y, float* __restrict__ mu,
                        float* __restrict__ rs) {
  int o = blockIdx.x, tid = threadIdx.x;
  float s = 0.f, s2 = 0.f;
  for (int b = 0; b < NB; ++b) {
    const float4* row = (const float4*)(y + (size_t)(b * OC + o) * MM);
    for (int m = tid; m < MM / 4; m += 256) {
      float4 v = row[m];
      s  += v.x + v.y + v.z + v.w;
      s2 += v.x * v.x + v.y * v.y + v.z * v.z + v.w * v.w;
    }
  }
#pragma unroll
  for (int off = 32; off; off >>= 1) { s += __shfl_down(s, off); s2 += __shfl_down(s2, off); }
  __shared__ float as[4], as2[4];
  int wv = tid >> 6, lane = tid & 63;
  if (lane == 0) { as[wv] = s; as2[wv] = s2; }
  __syncthreads();
  if (tid == 0) {
    float S  = as[0] + as[1] + as[2] + as[3];
    float S2 = as2[0] + as2[1] + as2[2] + as2[3];
    float mn = S / (float)(NB * MM);
    float vr = S2 / (float)(NB * MM) - mn * mn;
    mu[o] = mn;
    rs[o] = rsqrtf(vr + BNEPS);
  }
}

// ---------------------------------------------------------------- BN apply + LeakyReLU
__global__ void k_norm(float* __restrict__ y, const float* __restrict__ mu,
                       const float* __restrict__ rs, const float* __restrict__ gamma,
                       const float* __restrict__ beta) {
  int i = blockIdx.x * 256 + threadIdx.x;   // float4 index; grid covers exactly
  int o = (i >> 10) & 255;                  // 1024 float4 per (b,o) row
  float mn = mu[o], a = rs[o] * gamma[o], be = beta[o];
  float4 v = ((const float4*)y)[i];
  float t;
  t = (v.x - mn) * a + be; v.x = t >= 0.f ? t : SLOPE * t;
  t = (v.y - mn) * a + be; v.y = t >= 0.f ? t : SLOPE * t;
  t = (v.z - mn) * a + be; v.z = t >= 0.f ? t : SLOPE * t;
  t = (v.w - mn) * a + be; v.w = t >= 0.f ? t : SLOPE * t;
  ((float4*)y)[i] = v;
}

}  // namespace

extern "C" void kernel_launch(void* const* d_in, const int* in_sizes, int n_in,
                              void* d_out, int out_size, void* d_ws, size_t ws_size,
                              hipStream_t stream) {
  const float* dense = (const float*)d_in[0];
  const int*   didx  = (const int*)d_in[1];
  const float* sp    = (const float*)d_in[2];
  const int*   sidx  = (const int*)d_in[3];
  const float* pcd   = (const float*)d_in[4];
  const float* convw = (const float*)d_in[5];
  const float* gamma = (const float*)d_in[6];
  const float* beta  = (const float*)d_in[7];

  float* y = (float*)d_out;                       // [8][256][4096] raw -> normalized in place
  float* outIdxF = y + (size_t)NB * OC * MM;      // output 1: dense_idx as float

  char* ws = (char*)d_ws;                         // needs ~18 MB
  float* spt  = (float*)(ws + OFF_SPT);
  int*   idx3 = (int*)(ws + OFF_IDX3);
  float* w3   = (float*)(ws + OFF_W3);
  short* wbf  = (short*)(ws + OFF_WBF);
  float* mu   = (float*)(ws + OFF_MU);
  float* rs   = (float*)(ws + OFF_RS);

  k_wcast    <<<(OC * KTOT) / 256, 256, 0, stream>>>(convw, wbf);
  k_transpose<<<NB * (CS / 32) * (SS / 32), 256, 0, stream>>>(sp, spt);
  k_knn      <<<NB * (MM / 64), 256, 0, stream>>>(didx, sidx, pcd, idx3, w3, outIdxF);
  k_gemm     <<<NB * 2 * (MM / 128), 256, 0, stream>>>(dense, spt, idx3, w3, wbf, y);
  k_stats    <<<OC, 256, 0, stream>>>(y, mu, rs);
  k_norm     <<<(NB * OC * MM / 4) / 256, 256, 0, stream>>>(y, mu, rs, gamma, beta);
}